// Round 1
// baseline (357.968 us; speedup 1.0000x reference)
//
#include <hip/hip_runtime.h>
#include <hip/hip_bf16.h>
#include <stdint.h>

typedef __bf16 bf16_t;
typedef __bf16 bf16x8 __attribute__((ext_vector_type(8)));
typedef short short8 __attribute__((ext_vector_type(8)));
typedef float f32x4 __attribute__((ext_vector_type(4)));

#define RS512  0.044194173824159216f   // 1/sqrt(512)
#define RS4608 0.014731391274719739f   // 1/sqrt(512*9)

// ---------------- K1: style vector  s[b][c] = (w[b,:] . lw[c,:])/sqrt(512) + lb[c]
__global__ void k_style(const float* __restrict__ w, const float* __restrict__ lw,
                        const float* __restrict__ lb, float* __restrict__ s) {
  int b = blockIdx.y;
  int c = blockIdx.x * 256 + threadIdx.x;
  const float4* wr = (const float4*)(w + b * 512);
  const float4* lr = (const float4*)(lw + (size_t)c * 512);
  float acc = 0.f;
#pragma unroll 4
  for (int d = 0; d < 128; ++d) {
    float4 a = wr[d], q = lr[d];
    acc += a.x * q.x + a.y * q.y + a.z * q.z + a.w * q.w;
  }
  s[b * 512 + c] = acc * RS512 + lb[c];
}

// ---------------- K2: wsq[o][i] = sum_k (cw*r)^2 ; bw[tap][o][i] = bf16(cw*r)
__global__ void k_wprep(const float* __restrict__ cw, float* __restrict__ wsq,
                        bf16_t* __restrict__ bw) {
  int idx = blockIdx.x * 256 + threadIdx.x;  // o*512 + i
  float v[9];
  float ss = 0.f;
#pragma unroll
  for (int t = 0; t < 9; ++t) {
    float x = cw[(size_t)idx * 9 + t] * RS4608;
    v[t] = x;
    ss += x * x;
  }
  wsq[idx] = ss;
#pragma unroll
  for (int t = 0; t < 9; ++t) bw[((size_t)t << 18) + idx] = (bf16_t)v[t];
}

// ---------------- K3: sigma_inv[b][o] = rsqrt( sum_i s[b,i]^2 * wsq[o,i] + eps )
__global__ void k_sigma(const float* __restrict__ s, const float* __restrict__ wsq,
                        float* __restrict__ sinv) {
  __shared__ float s2[512];
  int b = blockIdx.y;
  int o = blockIdx.x * 256 + threadIdx.x;
  for (int i = threadIdx.x; i < 512; i += 256) {
    float v = s[b * 512 + i];
    s2[i] = v * v;
  }
  __syncthreads();
  const float4* qr = (const float4*)(wsq + (size_t)o * 512);
  float acc = 0.f;
#pragma unroll 4
  for (int d = 0; d < 128; ++d) {
    float4 q = qr[d];
    acc += q.x * s2[4 * d] + q.y * s2[4 * d + 1] + q.z * s2[4 * d + 2] + q.w * s2[4 * d + 3];
  }
  sinv[b * 512 + o] = rsqrtf(acc + 1e-8f);
}

// ---------------- K4: xt[b][h][w][i] = bf16( x[b][i][h][w] * s[b][i] )  (transpose via LDS)
__global__ void k_xt(const float* __restrict__ x, const float* __restrict__ s,
                     bf16_t* __restrict__ xt) {
  // grid (4, 64, 16) = (i-chunk of 128, h, b); block 256
  int ic = blockIdx.x, h = blockIdx.y, b = blockIdx.z;
  __shared__ __align__(16) bf16_t tile[8192];  // 64 w * 128 i, xor-swizzled 16B chunks
  int t = threadIdx.x;
  int wcol = t & 63;
  int g = t >> 6;
#pragma unroll
  for (int blk = 0; blk < 4; ++blk) {
    int grp = blk * 4 + g;  // i-group of 8, 0..15
    bf16x8 vec;
#pragma unroll
    for (int k = 0; k < 8; ++k) {
      int i = ic * 128 + grp * 8 + k;
      float v = x[(((size_t)b * 512 + i) * 64 + h) * 64 + wcol] * s[b * 512 + i];
      vec[k] = (bf16_t)v;
    }
    int chunk = grp ^ (wcol & 15);
    *(bf16x8*)((char*)tile + wcol * 256 + chunk * 16) = vec;
  }
  __syncthreads();
#pragma unroll
  for (int j = 0; j < 4; ++j) {
    int flat = j * 256 + t;
    int wo = flat >> 4, ig8 = flat & 15;
    int chunk = ig8 ^ (wo & 15);
    bf16x8 v = *(bf16x8*)((char*)tile + wo * 256 + chunk * 16);
    *(bf16x8*)(xt + (((size_t)b * 64 + h) * 64 + wo) * 512 + ic * 128 + ig8 * 8) = v;
  }
}

// ---------------- K5: implicit-GEMM conv + demod + noise + bias + leaky-relu
#define AS1 __attribute__((address_space(1)))
#define AS3 __attribute__((address_space(3)))

__device__ __forceinline__ void gl16(const void* g, void* l) {
  __builtin_amdgcn_global_load_lds((const AS1 void*)g, (AS3 void*)l, 16, 0, 0);
}

__global__ __launch_bounds__(256) void k_conv(
    const bf16_t* __restrict__ xt, const bf16_t* __restrict__ bw,
    const float* __restrict__ sinv, const float* __restrict__ noise,
    const float* __restrict__ snz, const float* __restrict__ bias,
    float* __restrict__ out) {
  // LDS: X[2][4 rows][64 cols][32 ch] bf16 @0 (16384 each buf)
  //      W[2][128 o][32 ch]          bf16 @32768 (8192 each buf)
  __shared__ __align__(16) char lds[49152];

  const int t = threadIdx.x;
  const int rp = blockIdx.x;         // row-pair 0..31
  const int o0 = blockIdx.y * 128;   // out-channel chunk
  const int b = blockIdx.z;
  const int h0 = rp * 2;
  const int lane = t & 63;
  const int wv = t >> 6;
  const int wm = wv >> 1, wn = wv & 1;  // wave tile: m-off wm*64, n-off wn*64

  const bf16_t* xb_base = xt + (size_t)b * 2097152;  // 64*64*512 per batch

  f32x4 acc[4][4] = {};

  auto stageX = [&](int c, int buf) {
    // stage rows h0-1 .. h0+2, chunk c (32 channels), 4KB per row, lane-linear dest
    char* ldst = lds + buf * 16384 + (wv << 10);
    const bf16_t* g0 = xb_base + (size_t)(t >> 2) * 512 + c * 32 + (t & 3) * 8;
#pragma unroll
    for (int r = 0; r < 4; ++r) {
      int gr = h0 - 1 + r;
      if ((unsigned)gr < 64u) {
        gl16(g0 + (size_t)gr * 32768, ldst + r * 4096);
      } else {
        *(f32x4*)(lds + buf * 16384 + r * 4096 + t * 16) = (f32x4)0.f;  // zero pad row
      }
    }
  };

  auto stageW = [&](int c, int tap, int buf) {
    char* ldst = lds + 32768 + buf * 8192 + (wv << 10);
    const bf16_t* g0 = bw + ((size_t)tap << 18) + (size_t)o0 * 512 + c * 32;
#pragma unroll
    for (int j = 0; j < 2; ++j) {
      int f = j * 256 + t;
      gl16(g0 + (size_t)(f >> 2) * 512 + (f & 3) * 8, ldst + j * 4096);
    }
  };

  // prologue
  stageX(0, 0);
  stageW(0, 0, 0);
  __syncthreads();

  for (int c = 0; c < 16; ++c) {
    const int xbuf = c & 1;
#pragma unroll
    for (int tap = 0; tap < 9; ++tap) {
      const int wb = (c + tap) & 1;
      // prefetch next step into the other buffers (loads stay in flight past compute)
      if (tap < 8) {
        stageW(c, tap + 1, wb ^ 1);
      } else if (c < 15) {
        stageW(c + 1, 0, wb ^ 1);
        stageX(c + 1, xbuf ^ 1);
      }
      // compute this step
      const int ky = tap / 3, kx = tap % 3;  // compile-time after unroll

      const char* wbase = lds + 32768 + wb * 8192 +
                          (wm * 64 + (lane & 15)) * 64 + (lane >> 4) * 16;
      bf16x8 af[4];
#pragma unroll
      for (int mi = 0; mi < 4; ++mi) af[mi] = *(const bf16x8*)(wbase + mi * 16 * 64);

      const char* xbase = lds + xbuf * 16384 + (wn + ky) * 4096 + (lane >> 4) * 16;
      bf16x8 bfr[4];
#pragma unroll
      for (int ni = 0; ni < 4; ++ni) {
        int icol = ni * 16 + (lane & 15) + kx - 1;
        bool valid = (unsigned)icol < 64u;
        int ic2 = valid ? icol : 0;
        short8 xv = *(const short8*)(xbase + ic2 * 64);
        if (!valid) xv = (short8)0;  // zero-pad left/right columns
        bfr[ni] = __builtin_bit_cast(bf16x8, xv);
      }
#pragma unroll
      for (int mi = 0; mi < 4; ++mi)
#pragma unroll
        for (int ni = 0; ni < 4; ++ni)
          acc[mi][ni] =
              __builtin_amdgcn_mfma_f32_16x16x32_bf16(af[mi], bfr[ni], acc[mi][ni], 0, 0, 0);
      __syncthreads();
    }
  }

  // epilogue: demod scale + noise + bias + leaky relu
  const float* sb = sinv + b * 512;
  const int orow_base = o0 + wm * 64 + ((lane >> 4) << 2);
  const int prow = h0 + wn;
  float nz[4];
#pragma unroll
  for (int ni = 0; ni < 4; ++ni)
    nz[ni] = noise[(size_t)b * 4096 + prow * 64 + ni * 16 + (lane & 15)];
#pragma unroll
  for (int mi = 0; mi < 4; ++mi) {
#pragma unroll
    for (int r = 0; r < 4; ++r) {
      int o = orow_base + mi * 16 + r;
      float sv = sb[o];
      float nw = snz[o];
      float bv = bias[o];
      float* orow = out + (((size_t)b * 512 + o) * 64 + prow) * 64;
#pragma unroll
      for (int ni = 0; ni < 4; ++ni) {
        int col = ni * 16 + (lane & 15);
        float v = acc[mi][ni][r] * sv + nw * nz[ni] + bv;
        orow[col] = v > 0.f ? v : 0.2f * v;
      }
    }
  }
}

extern "C" void kernel_launch(void* const* d_in, const int* in_sizes, int n_in,
                              void* d_out, int out_size, void* d_ws, size_t ws_size,
                              hipStream_t stream) {
  const float* x     = (const float*)d_in[0];
  const float* w     = (const float*)d_in[1];
  const float* noise = (const float*)d_in[2];
  const float* lw    = (const float*)d_in[3];
  const float* lb    = (const float*)d_in[4];
  const float* cw    = (const float*)d_in[5];
  const float* snz   = (const float*)d_in[6];
  const float* bias  = (const float*)d_in[7];
  float* out = (float*)d_out;

  char* ws = (char*)d_ws;
  bf16_t* xt   = (bf16_t*)ws;                   // 67,108,864 B : x' transposed bf16
  bf16_t* bw   = (bf16_t*)(ws + 67108864);      //  4,718,592 B : bf16 weights [tap][o][i]
  float*  s    = (float*)(ws + 71827456);       //     32,768 B
  float*  sinv = (float*)(ws + 71860224);       //     32,768 B
  float*  wsq  = (float*)(ws + 71892992);       //  1,048,576 B

  k_style<<<dim3(2, 16), 256, 0, stream>>>(w, lw, lb, s);
  k_wprep<<<dim3(1024), 256, 0, stream>>>(cw, wsq, bw);
  k_sigma<<<dim3(2, 16), 256, 0, stream>>>(s, wsq, sinv);
  k_xt<<<dim3(4, 64, 16), 256, 0, stream>>>(x, s, xt);
  k_conv<<<dim3(32, 4, 16), 256, 0, stream>>>(xt, bw, sinv, noise, snz, bias, out);
}